// Round 4
// baseline (390.545 us; speedup 1.0000x reference)
//
#include <hip/hip_runtime.h>
#include <hip/hip_fp16.h>

#define N_NODES  100000
#define N_EDGES  1000000
#define E_TOT    1100000   // edges + self-loops
#define E_CAP    1500000   // padded-CSR capacity (deg padded to x4: <= E_TOT + 3*N)
#define N_GRAPHS 64

__device__ __forceinline__ float elu_f(float v) {
    return v > 0.f ? v : expm1f(v);
}

__device__ __forceinline__ float lrelu(float v) {
    return v > 0.f ? v : 0.2f * v;
}

// ---------------------------------------------------------------------------
// K1: h1[n,c] = x[n,:4] . W1[c,:4]  (c = head*64+d, 128 cols), h1 stored fp16
// ---------------------------------------------------------------------------
__global__ void k_h1(const float* __restrict__ x, const float* __restrict__ w1,
                     const float* __restrict__ asrc, const float* __restrict__ adst,
                     __half* __restrict__ h1h, float* __restrict__ as1, float* __restrict__ ad1)
{
    __shared__ __align__(16) float sw[128 * 4];
    __shared__ float ssrc[128], sdst[128];
    for (int i = threadIdx.x; i < 512; i += blockDim.x) sw[i] = w1[i];
    for (int i = threadIdx.x; i < 128; i += blockDim.x) { ssrc[i] = asrc[i]; sdst[i] = adst[i]; }
    __syncthreads();

    int t = blockIdx.x * blockDim.x + threadIdx.x;   // grid sized exactly N*128
    int n = t >> 7, c = t & 127;
    const float4 xv = ((const float4*)x)[n];
    const float4 wv = ((const float4*)sw)[c];
    float h = xv.x * wv.x + xv.y * wv.y + xv.z * wv.z + xv.w * wv.w;
    h1h[t] = __float2half(h);

    float ps = h * ssrc[c];
    float pd = h * sdst[c];
    #pragma unroll
    for (int off = 32; off >= 1; off >>= 1) {
        ps += __shfl_xor(ps, off, 64);
        pd += __shfl_xor(pd, off, 64);
    }
    if ((c & 63) == 0) {
        int head = c >> 6;
        as1[n * 2 + head] = ps;
        ad1[n * 2 + head] = pd;
    }
}

// ---------------------------------------------------------------------------
// CSR build (padded): count -> scan(pad4) -> scatter(+layer-1 weights)
// ---------------------------------------------------------------------------
__global__ void k_count(const int* __restrict__ ei, int* __restrict__ deg, int* __restrict__ pos)
{
    int e = blockIdx.x * blockDim.x + threadIdx.x;
    if (e >= E_TOT) return;
    int dst = (e < N_EDGES) ? ei[N_EDGES + e] : (e - N_EDGES);
    pos[e] = atomicAdd(&deg[dst], 1);
}

// scans N_NODES+1 entries of pad4(deg); deg[N_NODES]==0 via memset
__global__ void k_scan1(const int* __restrict__ deg, int* __restrict__ rowptr, int* __restrict__ bsum)
{
    __shared__ int sh[256];
    int tid = threadIdx.x;
    int i = blockIdx.x * 256 + tid;
    int v = (i <= N_NODES) ? ((deg[i] + 3) & ~3) : 0;
    int acc = v;
    sh[tid] = acc; __syncthreads();
    for (int off = 1; off < 256; off <<= 1) {
        int add = (tid >= off) ? sh[tid - off] : 0;
        __syncthreads();
        acc += add;
        sh[tid] = acc;
        __syncthreads();
    }
    if (i <= N_NODES) rowptr[i] = acc - v;     // block-local exclusive
    if (tid == 255) bsum[blockIdx.x] = acc;    // block total
}

__global__ void k_scan2(int* __restrict__ bsum, int nb)
{
    __shared__ int sh[512];
    int tid = threadIdx.x;
    int v = (tid < nb) ? bsum[tid] : 0;
    int acc = v;
    sh[tid] = acc; __syncthreads();
    for (int off = 1; off < 512; off <<= 1) {
        int add = (tid >= off) ? sh[tid - off] : 0;
        __syncthreads();
        acc += add;
        sh[tid] = acc;
        __syncthreads();
    }
    if (tid < nb) bsum[tid] = acc - v;         // exclusive block offsets
}

__global__ void k_scan3(int* __restrict__ rowptr, const int* __restrict__ bsum)
{
    int i = blockIdx.x * 256 + threadIdx.x;
    if (i <= N_NODES) rowptr[i] += bsum[blockIdx.x];
}

// scatter srcs + layer-1 edge weights (both heads, plane layout), save jidx
__global__ void k_scatter_w1(const int* __restrict__ ei, const int* __restrict__ rowptr,
                             int* __restrict__ pos, int* __restrict__ srcs,
                             const float* __restrict__ as1, const float* __restrict__ ad1,
                             float* __restrict__ wcsr0, float* __restrict__ wcsr1)
{
    int e = blockIdx.x * blockDim.x + threadIdx.x;
    if (e >= E_TOT) return;
    int src = (e < N_EDGES) ? ei[e] : (e - N_EDGES);
    int dst = (e < N_EDGES) ? ei[N_EDGES + e] : (e - N_EDGES);
    int j = rowptr[dst] + pos[e];
    srcs[j] = src;
    pos[e] = j;                                // jidx for k_weights2
    float2 s = ((const float2*)as1)[src];
    float2 d = ((const float2*)ad1)[dst];
    wcsr0[j] = __expf(lrelu(s.x + d.x));
    wcsr1[j] = __expf(lrelu(s.y + d.y));
}

__global__ void k_weights2(const int* __restrict__ ei, const int* __restrict__ jidx,
                           const float* __restrict__ as2, const float* __restrict__ ad2,
                           float* __restrict__ wcsr)
{
    int e = blockIdx.x * blockDim.x + threadIdx.x;
    if (e >= E_TOT) return;
    int src = (e < N_EDGES) ? ei[e] : (e - N_EDGES);
    int dst = (e < N_EDGES) ? ei[N_EDGES + e] : (e - N_EDGES);
    wcsr[jidx[e]] = __expf(lrelu(as2[src] + ad2[dst]));
}

// ---------------------------------------------------------------------------
// Gather layer 1: wave per node, lane l = dims (2l,2l+1), head = l>>5.
// Rows padded to x4: int4 srcs + float4 weights per iter, no tail handling.
// ---------------------------------------------------------------------------
__global__ void __launch_bounds__(256) k_gather1(
    const int* __restrict__ srcs, const int* __restrict__ rowptr,
    const float* __restrict__ wcsr0,
    const __half* __restrict__ h1h, const float* __restrict__ b1,
    float* __restrict__ out1)
{
    const int tid  = threadIdx.x;
    const int n    = blockIdx.x * 4 + (tid >> 6);
    const int l    = tid & 63;
    const int head = l >> 5;
    if (n >= N_NODES) return;
    const int beg = rowptr[n], end = rowptr[n + 1];
    const __half2* __restrict__ h1v = (const __half2*)h1h;
    const float* __restrict__ wp = wcsr0 + (size_t)head * E_CAP;

    float2 acc = {0.f, 0.f};
    float wsum = 0.f;
    for (int j = beg; j < end; j += 4) {
        const int4   s4 = *(const int4*)(srcs + j);
        const float4 w4 = *(const float4*)(wp + j);
        const __half2 v0 = h1v[(size_t)s4.x * 64 + l];
        const __half2 v1 = h1v[(size_t)s4.y * 64 + l];
        const __half2 v2 = h1v[(size_t)s4.z * 64 + l];
        const __half2 v3 = h1v[(size_t)s4.w * 64 + l];
        acc.x = fmaf(w4.x, __half2float(v0.x), acc.x);
        acc.y = fmaf(w4.x, __half2float(v0.y), acc.y);
        acc.x = fmaf(w4.y, __half2float(v1.x), acc.x);
        acc.y = fmaf(w4.y, __half2float(v1.y), acc.y);
        acc.x = fmaf(w4.z, __half2float(v2.x), acc.x);
        acc.y = fmaf(w4.z, __half2float(v2.y), acc.y);
        acc.x = fmaf(w4.w, __half2float(v3.x), acc.x);
        acc.y = fmaf(w4.w, __half2float(v3.y), acc.y);
        wsum += (w4.x + w4.y) + (w4.z + w4.w);
    }
    const float2 bv = ((const float2*)b1)[l];
    float2 o;
    o.x = elu_f(acc.x / wsum + bv.x);
    o.y = elu_f(acc.y / wsum + bv.y);
    ((float2*)out1)[(size_t)n * 64 + l] = o;
}

// ---------------------------------------------------------------------------
// k_h2: 64 nodes/block, register-blocked 4 nodes x 4 dims per thread.
// ---------------------------------------------------------------------------
#define H2_NPB 64
#define SROW_LD 132
__global__ void __launch_bounds__(256) k_h2(
    const float* __restrict__ out1, const float* __restrict__ w2,
    const float* __restrict__ asrc, const float* __restrict__ adst,
    __half* __restrict__ h2h, float* __restrict__ as2, float* __restrict__ ad2)
{
    __shared__ __align__(16) float w2t[128 * 64];          // [k][d]  32 KB
    __shared__ __align__(16) float srow[H2_NPB * SROW_LD]; // 64 rows, padded
    const int tid = threadIdx.x;
    const int blockNode = blockIdx.x * H2_NPB;

    for (int i = tid; i < 128 * 64; i += 256) {
        int k = i >> 6, d = i & 63;
        w2t[i] = w2[d * 128 + k];
    }
    for (int i = tid; i < H2_NPB * 128; i += 256) {
        int r = i >> 7, col = i & 127;
        srow[r * SROW_LD + col] = out1[(size_t)blockNode * 128 + i];
    }
    __syncthreads();

    const int lane = tid & 63;
    const int wv   = tid >> 6;           // wave id 0..3
    const int q    = lane >> 4;          // node quad within wave
    const int dg   = lane & 15;          // dim group
    const int d_base    = dg * 4;
    const int node_base = wv * 16 + q * 4;

    float4 acc[4] = {{0,0,0,0},{0,0,0,0},{0,0,0,0},{0,0,0,0}};
    for (int k = 0; k < 128; k += 4) {
        const float4 w0 = *(const float4*)&w2t[(k + 0) * 64 + d_base];
        const float4 w1 = *(const float4*)&w2t[(k + 1) * 64 + d_base];
        const float4 wq = *(const float4*)&w2t[(k + 2) * 64 + d_base];
        const float4 w3 = *(const float4*)&w2t[(k + 3) * 64 + d_base];
        #pragma unroll
        for (int j = 0; j < 4; ++j) {
            const float4 rv = *(const float4*)&srow[(node_base + j) * SROW_LD + k];
            acc[j].x += rv.x * w0.x + rv.y * w1.x + rv.z * wq.x + rv.w * w3.x;
            acc[j].y += rv.x * w0.y + rv.y * w1.y + rv.z * wq.y + rv.w * w3.y;
            acc[j].z += rv.x * w0.z + rv.y * w1.z + rv.z * wq.z + rv.w * w3.z;
            acc[j].w += rv.x * w0.w + rv.y * w1.w + rv.z * wq.w + rv.w * w3.w;
        }
    }

    const float4 av = ((const float4*)asrc)[dg];
    const float4 dv = ((const float4*)adst)[dg];
    #pragma unroll
    for (int j = 0; j < 4; ++j) {
        int n = blockNode + node_base + j;
        float ps = acc[j].x * av.x + acc[j].y * av.y + acc[j].z * av.z + acc[j].w * av.w;
        float pd = acc[j].x * dv.x + acc[j].y * dv.y + acc[j].z * dv.z + acc[j].w * dv.w;
        #pragma unroll
        for (int off = 8; off >= 1; off >>= 1) {   // reduce across the 16 dim-groups
            ps += __shfl_xor(ps, off, 64);
            pd += __shfl_xor(pd, off, 64);
        }
        if (n < N_NODES) {
            __half2 p0 = __floats2half2_rn(acc[j].x, acc[j].y);
            __half2 p1 = __floats2half2_rn(acc[j].z, acc[j].w);
            ((__half2*)h2h)[(size_t)n * 32 + dg * 2]     = p0;
            ((__half2*)h2h)[(size_t)n * 32 + dg * 2 + 1] = p1;
            if (dg == 0) { as2[n] = ps; ad2[n] = pd; }
        }
    }
}

// ---------------------------------------------------------------------------
// Gather layer 2: wave per node, lane d = dim d (fp16 row), padded CSR
// ---------------------------------------------------------------------------
__global__ void __launch_bounds__(256) k_gather2(
    const int* __restrict__ srcs, const int* __restrict__ rowptr,
    const float* __restrict__ wcsr,
    const __half* __restrict__ h2h, const float* __restrict__ b2,
    float* __restrict__ out2)
{
    const int tid = threadIdx.x;
    const int n   = blockIdx.x * 4 + (tid >> 6);
    const int d   = tid & 63;
    if (n >= N_NODES) return;
    const int beg = rowptr[n], end = rowptr[n + 1];

    float acc = 0.f, wsum = 0.f;
    for (int j = beg; j < end; j += 4) {
        const int4   s4 = *(const int4*)(srcs + j);
        const float4 w4 = *(const float4*)(wcsr + j);
        const __half v0 = h2h[(size_t)s4.x * 64 + d];
        const __half v1 = h2h[(size_t)s4.y * 64 + d];
        const __half v2 = h2h[(size_t)s4.z * 64 + d];
        const __half v3 = h2h[(size_t)s4.w * 64 + d];
        acc = fmaf(w4.x, __half2float(v0), acc);
        acc = fmaf(w4.y, __half2float(v1), acc);
        acc = fmaf(w4.z, __half2float(v2), acc);
        acc = fmaf(w4.w, __half2float(v3), acc);
        wsum += (w4.x + w4.y) + (w4.z + w4.w);
    }
    out2[(size_t)n * 64 + d] = elu_f(acc / wsum + b2[d]);
}

// ---------------------------------------------------------------------------
// Global mean pool: batch sorted -> register runs, flush at boundaries
// ---------------------------------------------------------------------------
__global__ void __launch_bounds__(256) k_pool(
    const float* __restrict__ out2, const int* __restrict__ batch,
    float* __restrict__ pool, float* __restrict__ cnt)
{
    const int wv = threadIdx.x >> 6, d = threadIdx.x & 63;
    const int wid = blockIdx.x * 4 + wv;               // 2048 wave ranges
    const int per = (N_NODES + 2047) / 2048;           // 49
    int n0 = wid * per, n1 = min(n0 + per, N_NODES);
    if (n0 >= n1) return;
    float acc = 0.f; int g = batch[n0]; int run = 0;
    for (int n = n0; n < n1; ++n) {
        int gn = batch[n];
        if (gn != g) {
            atomicAdd(&pool[g * 64 + d], acc);
            if (d == 0) atomicAdd(&cnt[g], (float)run);
            acc = 0.f; run = 0; g = gn;
        }
        acc += out2[(size_t)n * 64 + d];
        ++run;
    }
    atomicAdd(&pool[g * 64 + d], acc);
    if (d == 0) atomicAdd(&cnt[g], (float)run);
}

__global__ void k_head(const float* __restrict__ pool, const float* __restrict__ cnt,
                       const float* __restrict__ wp, const float* __restrict__ bp,
                       float* __restrict__ out)
{
    int t = threadIdx.x;            // 1024 threads = 64 graphs x 16 outputs
    int g = t >> 4, s = t & 15;
    float c = cnt[g]; if (c < 1.f) c = 1.f;
    float acc = bp[s];
    for (int d = 0; d < 64; ++d) acc += (pool[g * 64 + d] / c) * wp[s * 64 + d];
    out[g * 16 + s] = acc;
}

extern "C" void kernel_launch(void* const* d_in, const int* in_sizes, int n_in,
                              void* d_out, int out_size, void* d_ws, size_t ws_size,
                              hipStream_t stream)
{
    const float* x     = (const float*)d_in[0];
    const int*   ei    = (const int*)  d_in[1];
    const int*   batch = (const int*)  d_in[2];
    const float* w1    = (const float*)d_in[3];
    const float* asr1  = (const float*)d_in[4];
    const float* adr1  = (const float*)d_in[5];
    const float* b1    = (const float*)d_in[6];
    const float* w2    = (const float*)d_in[7];
    const float* asr2  = (const float*)d_in[8];
    const float* adr2  = (const float*)d_in[9];
    const float* b2    = (const float*)d_in[10];
    const float* wp    = (const float*)d_in[11];
    const float* bp    = (const float*)d_in[12];
    float* out = (float*)d_out;

    // Workspace layout (~103 MB)
    __half* h1h = (__half*)d_ws;                          // N*128 fp16; h2h overlays
    float* out1 = (float*)(h1h + (size_t)N_NODES * 128);  // N*128 f32; out2 overlays
    float* as1  = out1 + (size_t)N_NODES * 128;           // N*2
    float* ad1  = as1 + N_NODES * 2;                      // N*2
    float* as2  = ad1 + N_NODES * 2;                      // N
    float* ad2  = as2 + N_NODES;                          // N
    float* pool = ad2 + N_NODES;                          // 64*64
    float* cnt  = pool + N_GRAPHS * 64;                   // 64
    int* deg    = (int*)(cnt + N_GRAPHS);                 // N+1
    int* rowptr = deg + N_NODES + 1;                      // N+1
    int* pos    = rowptr + N_NODES + 1;                   // E_TOT (count pos -> jidx)
    int* srcs   = pos + E_TOT;                            // E_CAP  (zeroed: pads -> node 0)
    float* wcsr0 = (float*)(srcs + E_CAP);                // E_CAP plane head0 / layer2
    float* wcsr1 = wcsr0 + E_CAP;                         // E_CAP plane head1
    int* bsum   = (int*)(wcsr1 + E_CAP);                  // 512 scan scratch
    __half* h2h = h1h;
    float* out2 = out1;

    hipMemsetAsync(deg, 0, (size_t)(N_NODES + 1) * sizeof(int), stream);
    hipMemsetAsync(pool, 0, (size_t)(N_GRAPHS * 64 + N_GRAPHS) * sizeof(float), stream);
    hipMemsetAsync(srcs, 0, (size_t)E_CAP * 3 * sizeof(int), stream);  // srcs+wcsr0+wcsr1

    // Layer-1 projection + attention coefficients
    k_h1<<<(N_NODES * 128) / 256, 256, 0, stream>>>(x, w1, asr1, adr1, h1h, as1, ad1);

    // Padded CSR by destination
    const int eb  = (E_TOT + 255) / 256;
    const int nb1 = (N_NODES + 1 + 255) / 256;   // 391
    k_count<<<eb, 256, 0, stream>>>(ei, deg, pos);
    k_scan1<<<nb1, 256, 0, stream>>>(deg, rowptr, bsum);
    k_scan2<<<1, 512, 0, stream>>>(bsum, nb1);
    k_scan3<<<nb1, 256, 0, stream>>>(rowptr, bsum);
    k_scatter_w1<<<eb, 256, 0, stream>>>(ei, rowptr, pos, srcs, as1, ad1, wcsr0, wcsr1);

    // Layer 1 aggregate + ELU
    k_gather1<<<(N_NODES + 3) / 4, 256, 0, stream>>>(srcs, rowptr, wcsr0, h1h, b1, out1);

    // Layer-2 projection + attention coefficients (writes fp16 h2)
    k_h2<<<(N_NODES + H2_NPB - 1) / H2_NPB, 256, 0, stream>>>(out1, w2, asr2, adr2, h2h, as2, ad2);

    // Layer-2 edge weights + aggregate + ELU (reuses wcsr0 plane; pads still 0)
    k_weights2<<<eb, 256, 0, stream>>>(ei, pos, as2, ad2, wcsr0);
    k_gather2<<<(N_NODES + 3) / 4, 256, 0, stream>>>(srcs, rowptr, wcsr0, h2h, b2, out2);

    // Mean pool + head
    k_pool<<<512, 256, 0, stream>>>(out2, batch, pool, cnt);
    k_head<<<1, 1024, 0, stream>>>(pool, cnt, wp, bp, out);
}

// Round 5
// 317.525 us; speedup vs baseline: 1.2300x; 1.2300x over previous
//
#include <hip/hip_runtime.h>
#include <hip/hip_fp16.h>

#define N_NODES  100000
#define N_EDGES  1000000
#define E_TOT    1100000   // edges + self-loops
#define E_CAP    1500000   // padded-CSR capacity (deg padded to x4: <= E_TOT + 3*N)
#define N_GRAPHS 64

__device__ __forceinline__ float elu_f(float v) {
    return v > 0.f ? v : expm1f(v);
}

__device__ __forceinline__ float lrelu(float v) {
    return v > 0.f ? v : 0.2f * v;
}

// ---------------------------------------------------------------------------
// k_pre: fold attention vectors through the weight matrices (exact algebra):
//   A1[h][k] = sum_d W1[(h*64+d)*4+k] * a_src1[h*64+d]   (as1[n,h] = x[n,:].A1[h])
//   D1 likewise with a_dst1
//   B2[k]    = sum_d W2[d*128+k] * a_src2[d]             (as2[n] = out1[n,:].B2)
//   E2 likewise with a_dst2
// ---------------------------------------------------------------------------
__global__ void k_pre(const float* __restrict__ w1,
                      const float* __restrict__ as1v, const float* __restrict__ ad1v,
                      const float* __restrict__ w2,
                      const float* __restrict__ as2v, const float* __restrict__ ad2v,
                      float* __restrict__ A1, float* __restrict__ D1,
                      float* __restrict__ B2, float* __restrict__ E2)
{
    int t = threadIdx.x;
    if (t < 128) {
        float acc = 0.f;
        for (int d = 0; d < 64; ++d) acc += w2[d * 128 + t] * as2v[d];
        B2[t] = acc;
    } else {
        int k = t - 128;
        float acc = 0.f;
        for (int d = 0; d < 64; ++d) acc += w2[d * 128 + k] * ad2v[d];
        E2[k] = acc;
    }
    if (t < 8) {
        int h = t >> 2, k = t & 3;
        float acc = 0.f;
        for (int d = 0; d < 64; ++d) acc += w1[(h * 64 + d) * 4 + k] * as1v[h * 64 + d];
        A1[t] = acc;
    } else if (t < 16) {
        int i = t - 8, h = i >> 2, k = i & 3;
        float acc = 0.f;
        for (int d = 0; d < 64; ++d) acc += w1[(h * 64 + d) * 4 + k] * ad1v[h * 64 + d];
        D1[i] = acc;
    }
}

// ---------------------------------------------------------------------------
// k_h1: pure projection, 4 channels/thread, fp16 store. No shuffles.
// ---------------------------------------------------------------------------
__global__ void __launch_bounds__(256) k_h1(
    const float* __restrict__ x, const float* __restrict__ w1, __half* __restrict__ h1h)
{
    __shared__ __align__(16) float4 sw[128];
    for (int i = threadIdx.x; i < 128; i += 256) sw[i] = ((const float4*)w1)[i];
    __syncthreads();
    int t = blockIdx.x * 256 + threadIdx.x;     // grid = N*32 exactly
    int n = t >> 5, p = t & 31;                 // channels 4p..4p+3
    const float4 xv = ((const float4*)x)[n];
    const float4 w0 = sw[4 * p + 0];
    const float4 w1v = sw[4 * p + 1];
    const float4 w2v = sw[4 * p + 2];
    const float4 w3v = sw[4 * p + 3];
    float h0 = xv.x * w0.x + xv.y * w0.y + xv.z * w0.z + xv.w * w0.w;
    float h1 = xv.x * w1v.x + xv.y * w1v.y + xv.z * w1v.z + xv.w * w1v.w;
    float h2 = xv.x * w2v.x + xv.y * w2v.y + xv.z * w2v.z + xv.w * w2v.w;
    float h3 = xv.x * w3v.x + xv.y * w3v.y + xv.z * w3v.z + xv.w * w3v.w;
    __half2 lo = __floats2half2_rn(h0, h1);
    __half2 hi = __floats2half2_rn(h2, h3);
    uint2 val;
    val.x = *(unsigned int*)&lo;
    val.y = *(unsigned int*)&hi;
    ((uint2*)h1h)[(size_t)n * 32 + p] = val;
}

// ---------------------------------------------------------------------------
// k_att1: as1/ad1 directly from x via A1/D1 (4-dim dots)
// ---------------------------------------------------------------------------
__global__ void k_att1(const float* __restrict__ x,
                       const float* __restrict__ A1, const float* __restrict__ D1,
                       float* __restrict__ as1, float* __restrict__ ad1)
{
    int n = blockIdx.x * blockDim.x + threadIdx.x;
    if (n >= N_NODES) return;
    const float4 xv = ((const float4*)x)[n];
    const float4 a0 = ((const float4*)A1)[0], a1 = ((const float4*)A1)[1];
    const float4 d0 = ((const float4*)D1)[0], d1 = ((const float4*)D1)[1];
    float2 s, d;
    s.x = xv.x * a0.x + xv.y * a0.y + xv.z * a0.z + xv.w * a0.w;
    s.y = xv.x * a1.x + xv.y * a1.y + xv.z * a1.z + xv.w * a1.w;
    d.x = xv.x * d0.x + xv.y * d0.y + xv.z * d0.z + xv.w * d0.w;
    d.y = xv.x * d1.x + xv.y * d1.y + xv.z * d1.z + xv.w * d1.w;
    ((float2*)as1)[n] = s;
    ((float2*)ad1)[n] = d;
}

// ---------------------------------------------------------------------------
// CSR build (padded): count -> scan(pad4) -> scatter (srcs only)
// ---------------------------------------------------------------------------
__global__ void k_count(const int* __restrict__ ei, int* __restrict__ deg, int* __restrict__ pos)
{
    int e = blockIdx.x * blockDim.x + threadIdx.x;
    if (e >= E_TOT) return;
    int dst = (e < N_EDGES) ? ei[N_EDGES + e] : (e - N_EDGES);
    pos[e] = atomicAdd(&deg[dst], 1);
}

__global__ void k_scan1(const int* __restrict__ deg, int* __restrict__ rowptr, int* __restrict__ bsum)
{
    __shared__ int sh[256];
    int tid = threadIdx.x;
    int i = blockIdx.x * 256 + tid;
    int v = (i <= N_NODES) ? ((deg[i] + 3) & ~3) : 0;
    int acc = v;
    sh[tid] = acc; __syncthreads();
    for (int off = 1; off < 256; off <<= 1) {
        int add = (tid >= off) ? sh[tid - off] : 0;
        __syncthreads();
        acc += add;
        sh[tid] = acc;
        __syncthreads();
    }
    if (i <= N_NODES) rowptr[i] = acc - v;
    if (tid == 255) bsum[blockIdx.x] = acc;
}

__global__ void k_scan2(int* __restrict__ bsum, int nb)
{
    __shared__ int sh[512];
    int tid = threadIdx.x;
    int v = (tid < nb) ? bsum[tid] : 0;
    int acc = v;
    sh[tid] = acc; __syncthreads();
    for (int off = 1; off < 512; off <<= 1) {
        int add = (tid >= off) ? sh[tid - off] : 0;
        __syncthreads();
        acc += add;
        sh[tid] = acc;
        __syncthreads();
    }
    if (tid < nb) bsum[tid] = acc - v;
}

__global__ void k_scan3(int* __restrict__ rowptr, const int* __restrict__ bsum)
{
    int i = blockIdx.x * 256 + threadIdx.x;
    if (i <= N_NODES) rowptr[i] += bsum[blockIdx.x];
}

__global__ void k_scatter(const int* __restrict__ ei, const int* __restrict__ rowptr,
                          const int* __restrict__ pos, int* __restrict__ srcs)
{
    int e = blockIdx.x * blockDim.x + threadIdx.x;
    if (e >= E_TOT) return;
    int src = (e < N_EDGES) ? ei[e] : (e - N_EDGES);
    int dst = (e < N_EDGES) ? ei[N_EDGES + e] : (e - N_EDGES);
    srcs[rowptr[dst] + pos[e]] = src;
}

// ---------------------------------------------------------------------------
// Edge weights in CSR order, node-parallel (16-lane group per node):
// sequential srcs read, COALESCED weight writes; pads zeroed explicitly.
// ---------------------------------------------------------------------------
__global__ void __launch_bounds__(256) k_weights1(
    const int* __restrict__ rowptr, const int* __restrict__ deg, int* __restrict__ srcs,
    const float* __restrict__ as1, const float* __restrict__ ad1,
    float* __restrict__ w0p, float* __restrict__ w1p)
{
    int n = blockIdx.x * 16 + (threadIdx.x >> 4);
    int lane = threadIdx.x & 15;
    if (n >= N_NODES) return;
    int beg = rowptr[n], pend = rowptr[n + 1], rend = beg + deg[n];
    float2 dv = ((const float2*)ad1)[n];
    for (int j = beg + lane; j < pend; j += 16) {
        if (j < rend) {
            int s = srcs[j];
            float2 sv = ((const float2*)as1)[s];
            w0p[j] = __expf(lrelu(sv.x + dv.x));
            w1p[j] = __expf(lrelu(sv.y + dv.y));
        } else {
            srcs[j] = 0;        // pad: safe row, zero weight
            w0p[j] = 0.f;
            w1p[j] = 0.f;
        }
    }
}

__global__ void __launch_bounds__(256) k_weights2(
    const int* __restrict__ rowptr, const int* __restrict__ deg, const int* __restrict__ srcs,
    const float* __restrict__ as2, const float* __restrict__ ad2,
    float* __restrict__ w0p)
{
    int n = blockIdx.x * 16 + (threadIdx.x >> 4);
    int lane = threadIdx.x & 15;
    if (n >= N_NODES) return;
    int beg = rowptr[n], pend = rowptr[n + 1], rend = beg + deg[n];
    float adv = ad2[n];
    for (int j = beg + lane; j < pend; j += 16) {
        w0p[j] = (j < rend) ? __expf(lrelu(as2[srcs[j]] + adv)) : 0.f;
    }
}

// ---------------------------------------------------------------------------
// Gather layer 1: wave per node, lane l = dims (2l,2l+1), head = l>>5.
// Epilogue also produces as2/ad2 = out1-row . B2/E2 (shuffle reduce).
// ---------------------------------------------------------------------------
__global__ void __launch_bounds__(256) k_gather1(
    const int* __restrict__ srcs, const int* __restrict__ rowptr,
    const float* __restrict__ wcsr0,
    const __half* __restrict__ h1h, const float* __restrict__ b1,
    const float* __restrict__ B2, const float* __restrict__ E2,
    float* __restrict__ out1, float* __restrict__ as2, float* __restrict__ ad2)
{
    const int tid  = threadIdx.x;
    const int n    = blockIdx.x * 4 + (tid >> 6);
    const int l    = tid & 63;
    const int head = l >> 5;
    if (n >= N_NODES) return;
    const int beg = rowptr[n], end = rowptr[n + 1];
    const __half2* __restrict__ h1v = (const __half2*)h1h;
    const float* __restrict__ wp = wcsr0 + (size_t)head * E_CAP;

    float2 acc = {0.f, 0.f};
    float wsum = 0.f;
    for (int j = beg; j < end; j += 4) {
        const int4   s4 = *(const int4*)(srcs + j);
        const float4 w4 = *(const float4*)(wp + j);
        const __half2 v0 = h1v[(size_t)s4.x * 64 + l];
        const __half2 v1 = h1v[(size_t)s4.y * 64 + l];
        const __half2 v2 = h1v[(size_t)s4.z * 64 + l];
        const __half2 v3 = h1v[(size_t)s4.w * 64 + l];
        acc.x = fmaf(w4.x, __half2float(v0.x), acc.x);
        acc.y = fmaf(w4.x, __half2float(v0.y), acc.y);
        acc.x = fmaf(w4.y, __half2float(v1.x), acc.x);
        acc.y = fmaf(w4.y, __half2float(v1.y), acc.y);
        acc.x = fmaf(w4.z, __half2float(v2.x), acc.x);
        acc.y = fmaf(w4.z, __half2float(v2.y), acc.y);
        acc.x = fmaf(w4.w, __half2float(v3.x), acc.x);
        acc.y = fmaf(w4.w, __half2float(v3.y), acc.y);
        wsum += (w4.x + w4.y) + (w4.z + w4.w);
    }
    const float2 bv = ((const float2*)b1)[l];
    float2 o;
    o.x = elu_f(acc.x / wsum + bv.x);
    o.y = elu_f(acc.y / wsum + bv.y);
    ((float2*)out1)[(size_t)n * 64 + l] = o;

    // layer-2 attention coefficients from the finished out1 row
    const float2 Bv = ((const float2*)B2)[l];
    const float2 Ev = ((const float2*)E2)[l];
    float ps = o.x * Bv.x + o.y * Bv.y;
    float pd = o.x * Ev.x + o.y * Ev.y;
    #pragma unroll
    for (int off = 32; off >= 1; off >>= 1) {
        ps += __shfl_xor(ps, off, 64);
        pd += __shfl_xor(pd, off, 64);
    }
    if (l == 0) { as2[n] = ps; ad2[n] = pd; }
}

// ---------------------------------------------------------------------------
// k_h2: 64 nodes/block, register-blocked 4 nodes x 4 dims per thread. GEMM only.
// ---------------------------------------------------------------------------
#define H2_NPB 64
#define SROW_LD 132
__global__ void __launch_bounds__(256) k_h2(
    const float* __restrict__ out1, const float* __restrict__ w2,
    __half* __restrict__ h2h)
{
    __shared__ __align__(16) float w2t[128 * 64];          // [k][d]  32 KB
    __shared__ __align__(16) float srow[H2_NPB * SROW_LD]; // 64 rows, padded
    const int tid = threadIdx.x;
    const int blockNode = blockIdx.x * H2_NPB;

    for (int i = tid; i < 128 * 64; i += 256) {
        int k = i >> 6, d = i & 63;
        w2t[i] = w2[d * 128 + k];
    }
    for (int i = tid; i < H2_NPB * 128; i += 256) {
        int r = i >> 7, col = i & 127;
        srow[r * SROW_LD + col] = out1[(size_t)blockNode * 128 + i];
    }
    __syncthreads();

    const int lane = tid & 63;
    const int wv   = tid >> 6;
    const int q    = lane >> 4;
    const int dg   = lane & 15;
    const int d_base    = dg * 4;
    const int node_base = wv * 16 + q * 4;

    float4 acc[4] = {{0,0,0,0},{0,0,0,0},{0,0,0,0},{0,0,0,0}};
    for (int k = 0; k < 128; k += 4) {
        const float4 w0 = *(const float4*)&w2t[(k + 0) * 64 + d_base];
        const float4 w1 = *(const float4*)&w2t[(k + 1) * 64 + d_base];
        const float4 wq = *(const float4*)&w2t[(k + 2) * 64 + d_base];
        const float4 w3 = *(const float4*)&w2t[(k + 3) * 64 + d_base];
        #pragma unroll
        for (int j = 0; j < 4; ++j) {
            const float4 rv = *(const float4*)&srow[(node_base + j) * SROW_LD + k];
            acc[j].x += rv.x * w0.x + rv.y * w1.x + rv.z * wq.x + rv.w * w3.x;
            acc[j].y += rv.x * w0.y + rv.y * w1.y + rv.z * wq.y + rv.w * w3.y;
            acc[j].z += rv.x * w0.z + rv.y * w1.z + rv.z * wq.z + rv.w * w3.z;
            acc[j].w += rv.x * w0.w + rv.y * w1.w + rv.z * wq.w + rv.w * w3.w;
        }
    }

    #pragma unroll
    for (int j = 0; j < 4; ++j) {
        int n = blockNode + node_base + j;
        if (n < N_NODES) {
            __half2 p0 = __floats2half2_rn(acc[j].x, acc[j].y);
            __half2 p1 = __floats2half2_rn(acc[j].z, acc[j].w);
            ((__half2*)h2h)[(size_t)n * 32 + dg * 2]     = p0;
            ((__half2*)h2h)[(size_t)n * 32 + dg * 2 + 1] = p1;
        }
    }
}

// ---------------------------------------------------------------------------
// Gather layer 2: wave per node, lane d = dim d (fp16 row), padded CSR
// ---------------------------------------------------------------------------
__global__ void __launch_bounds__(256) k_gather2(
    const int* __restrict__ srcs, const int* __restrict__ rowptr,
    const float* __restrict__ wcsr,
    const __half* __restrict__ h2h, const float* __restrict__ b2,
    float* __restrict__ out2)
{
    const int tid = threadIdx.x;
    const int n   = blockIdx.x * 4 + (tid >> 6);
    const int d   = tid & 63;
    if (n >= N_NODES) return;
    const int beg = rowptr[n], end = rowptr[n + 1];

    float acc = 0.f, wsum = 0.f;
    for (int j = beg; j < end; j += 4) {
        const int4   s4 = *(const int4*)(srcs + j);
        const float4 w4 = *(const float4*)(wcsr + j);
        const __half v0 = h2h[(size_t)s4.x * 64 + d];
        const __half v1 = h2h[(size_t)s4.y * 64 + d];
        const __half v2 = h2h[(size_t)s4.z * 64 + d];
        const __half v3 = h2h[(size_t)s4.w * 64 + d];
        acc = fmaf(w4.x, __half2float(v0), acc);
        acc = fmaf(w4.y, __half2float(v1), acc);
        acc = fmaf(w4.z, __half2float(v2), acc);
        acc = fmaf(w4.w, __half2float(v3), acc);
        wsum += (w4.x + w4.y) + (w4.z + w4.w);
    }
    out2[(size_t)n * 64 + d] = elu_f(acc / wsum + b2[d]);
}

// ---------------------------------------------------------------------------
// Global mean pool: batch sorted -> register runs, flush at boundaries
// ---------------------------------------------------------------------------
__global__ void __launch_bounds__(256) k_pool(
    const float* __restrict__ out2, const int* __restrict__ batch,
    float* __restrict__ pool, float* __restrict__ cnt)
{
    const int wv = threadIdx.x >> 6, d = threadIdx.x & 63;
    const int wid = blockIdx.x * 4 + wv;
    const int per = (N_NODES + 2047) / 2048;
    int n0 = wid * per, n1 = min(n0 + per, N_NODES);
    if (n0 >= n1) return;
    float acc = 0.f; int g = batch[n0]; int run = 0;
    for (int n = n0; n < n1; ++n) {
        int gn = batch[n];
        if (gn != g) {
            atomicAdd(&pool[g * 64 + d], acc);
            if (d == 0) atomicAdd(&cnt[g], (float)run);
            acc = 0.f; run = 0; g = gn;
        }
        acc += out2[(size_t)n * 64 + d];
        ++run;
    }
    atomicAdd(&pool[g * 64 + d], acc);
    if (d == 0) atomicAdd(&cnt[g], (float)run);
}

__global__ void k_head(const float* __restrict__ pool, const float* __restrict__ cnt,
                       const float* __restrict__ wp, const float* __restrict__ bp,
                       float* __restrict__ out)
{
    int t = threadIdx.x;
    int g = t >> 4, s = t & 15;
    float c = cnt[g]; if (c < 1.f) c = 1.f;
    float acc = bp[s];
    for (int d = 0; d < 64; ++d) acc += (pool[g * 64 + d] / c) * wp[s * 64 + d];
    out[g * 16 + s] = acc;
}

extern "C" void kernel_launch(void* const* d_in, const int* in_sizes, int n_in,
                              void* d_out, int out_size, void* d_ws, size_t ws_size,
                              hipStream_t stream)
{
    const float* x     = (const float*)d_in[0];
    const int*   ei    = (const int*)  d_in[1];
    const int*   batch = (const int*)  d_in[2];
    const float* w1    = (const float*)d_in[3];
    const float* asr1  = (const float*)d_in[4];
    const float* adr1  = (const float*)d_in[5];
    const float* b1    = (const float*)d_in[6];
    const float* w2    = (const float*)d_in[7];
    const float* asr2  = (const float*)d_in[8];
    const float* adr2  = (const float*)d_in[9];
    const float* b2    = (const float*)d_in[10];
    const float* wp    = (const float*)d_in[11];
    const float* bp    = (const float*)d_in[12];
    float* out = (float*)d_out;

    // Workspace layout (~103 MB)
    __half* h1h = (__half*)d_ws;                          // N*128 fp16; h2h overlays
    float* out1 = (float*)(h1h + (size_t)N_NODES * 128);  // N*128 f32; out2 overlays
    float* as1  = out1 + (size_t)N_NODES * 128;           // N*2
    float* ad1  = as1 + N_NODES * 2;                      // N*2
    float* as2  = ad1 + N_NODES * 2;                      // N
    float* ad2  = as2 + N_NODES;                          // N
    float* pool = ad2 + N_NODES;                          // 64*64
    float* cnt  = pool + N_GRAPHS * 64;                   // 64
    int* deg    = (int*)(cnt + N_GRAPHS);                 // N+1
    int* rowptr = deg + N_NODES + 1;                      // N+1
    int* pos    = rowptr + N_NODES + 1;                   // E_TOT
    int* srcs   = pos + E_TOT;                            // E_CAP
    float* wcsr0 = (float*)(srcs + E_CAP);                // E_CAP plane head0 / layer2
    float* wcsr1 = wcsr0 + E_CAP;                         // E_CAP plane head1
    int* bsum   = (int*)(wcsr1 + E_CAP);                  // 512 scan scratch
    float* A1   = (float*)(bsum + 512);                   // 8
    float* D1   = A1 + 8;                                 // 8
    float* B2   = D1 + 8;                                 // 128
    float* E2   = B2 + 128;                               // 128
    __half* h2h = h1h;
    float* out2 = out1;

    hipMemsetAsync(deg, 0, (size_t)(N_NODES + 1) * sizeof(int), stream);
    hipMemsetAsync(pool, 0, (size_t)(N_GRAPHS * 64 + N_GRAPHS) * sizeof(float), stream);

    // Folded attention projections + layer-1 projection + node att coefficients
    k_pre<<<1, 256, 0, stream>>>(w1, asr1, adr1, w2, asr2, adr2, A1, D1, B2, E2);
    k_h1<<<(N_NODES * 32) / 256, 256, 0, stream>>>(x, w1, h1h);
    k_att1<<<(N_NODES + 255) / 256, 256, 0, stream>>>(x, A1, D1, as1, ad1);

    // Padded CSR by destination
    const int eb  = (E_TOT + 255) / 256;
    const int nb1 = (N_NODES + 1 + 255) / 256;
    k_count<<<eb, 256, 0, stream>>>(ei, deg, pos);
    k_scan1<<<nb1, 256, 0, stream>>>(deg, rowptr, bsum);
    k_scan2<<<1, 512, 0, stream>>>(bsum, nb1);
    k_scan3<<<nb1, 256, 0, stream>>>(rowptr, bsum);
    k_scatter<<<eb, 256, 0, stream>>>(ei, rowptr, pos, srcs);

    // Layer-1 weights (coalesced CSR writes, pads zeroed) + aggregate
    const int wb = (N_NODES + 15) / 16;
    k_weights1<<<wb, 256, 0, stream>>>(rowptr, deg, srcs, as1, ad1, wcsr0, wcsr1);
    k_gather1<<<(N_NODES + 3) / 4, 256, 0, stream>>>(srcs, rowptr, wcsr0, h1h, b1,
                                                     B2, E2, out1, as2, ad2);

    // Layer-2 projection (GEMM only)
    k_h2<<<(N_NODES + H2_NPB - 1) / H2_NPB, 256, 0, stream>>>(out1, w2, h2h);

    // Layer-2 weights + aggregate
    k_weights2<<<wb, 256, 0, stream>>>(rowptr, deg, srcs, as2, ad2, wcsr0);
    k_gather2<<<(N_NODES + 3) / 4, 256, 0, stream>>>(srcs, rowptr, wcsr0, h2h, b2, out2);

    // Mean pool + head
    k_pool<<<512, 256, 0, stream>>>(out2, batch, pool, cnt);
    k_head<<<1, 1024, 0, stream>>>(pool, cnt, wp, bp, out);
}

// Round 6
// 259.666 us; speedup vs baseline: 1.5040x; 1.2228x over previous
//
#include <hip/hip_runtime.h>
#include <hip/hip_fp16.h>

#define N_NODES  100000
#define N_EDGES  1000000
#define E_TOT    1100000   // edges + self-loops
#define E_CAP    1500000   // padded-CSR capacity (deg padded to x4)
#define N_GRAPHS 64

__device__ __forceinline__ float elu_f(float v) {
    return v > 0.f ? v : expm1f(v);
}

__device__ __forceinline__ float lrelu(float v) {
    return v > 0.f ? v : 0.2f * v;
}

// ---------------------------------------------------------------------------
// k_pre: fold attention vectors through weights (exact algebra):
//   A1[h*4+k] = sum_d W1[(h*64+d)*4+k]*a_src1[h*64+d]  -> as1[n,h] = x[n,:].A1[h]
//   D1 likewise (a_dst1);  B2[k] = sum_d W2[d*128+k]*a_src2[d];  E2 likewise
// ---------------------------------------------------------------------------
__global__ void k_pre(const float* __restrict__ w1,
                      const float* __restrict__ as1v, const float* __restrict__ ad1v,
                      const float* __restrict__ w2,
                      const float* __restrict__ as2v, const float* __restrict__ ad2v,
                      float* __restrict__ A1, float* __restrict__ D1,
                      float* __restrict__ B2, float* __restrict__ E2)
{
    int t = threadIdx.x;
    if (t < 128) {
        float acc = 0.f;
        for (int d = 0; d < 64; ++d) acc += w2[d * 128 + t] * as2v[d];
        B2[t] = acc;
    } else {
        int k = t - 128;
        float acc = 0.f;
        for (int d = 0; d < 64; ++d) acc += w2[d * 128 + k] * ad2v[d];
        E2[k] = acc;
    }
    if (t < 8) {
        int h = t >> 2, k = t & 3;
        float acc = 0.f;
        for (int d = 0; d < 64; ++d) acc += w1[(h * 64 + d) * 4 + k] * as1v[h * 64 + d];
        A1[t] = acc;
    } else if (t < 16) {
        int i = t - 8, h = i >> 2, k = i & 3;
        float acc = 0.f;
        for (int d = 0; d < 64; ++d) acc += w1[(h * 64 + d) * 4 + k] * ad1v[h * 64 + d];
        D1[i] = acc;
    }
}

// ---------------------------------------------------------------------------
// CSR build (padded): count -> scan(pad4) -> scatter (srcs only)
// ---------------------------------------------------------------------------
__global__ void k_count(const int* __restrict__ ei, int* __restrict__ deg, int* __restrict__ pos)
{
    int e = blockIdx.x * blockDim.x + threadIdx.x;
    if (e >= E_TOT) return;
    int dst = (e < N_EDGES) ? ei[N_EDGES + e] : (e - N_EDGES);
    pos[e] = atomicAdd(&deg[dst], 1);
}

__global__ void k_scan1(const int* __restrict__ deg, int* __restrict__ rowptr, int* __restrict__ bsum)
{
    __shared__ int sh[256];
    int tid = threadIdx.x;
    int i = blockIdx.x * 256 + tid;
    int v = (i <= N_NODES) ? ((deg[i] + 3) & ~3) : 0;
    int acc = v;
    sh[tid] = acc; __syncthreads();
    for (int off = 1; off < 256; off <<= 1) {
        int add = (tid >= off) ? sh[tid - off] : 0;
        __syncthreads();
        acc += add;
        sh[tid] = acc;
        __syncthreads();
    }
    if (i <= N_NODES) rowptr[i] = acc - v;
    if (tid == 255) bsum[blockIdx.x] = acc;
}

__global__ void k_scan2(int* __restrict__ bsum, int nb)
{
    __shared__ int sh[512];
    int tid = threadIdx.x;
    int v = (tid < nb) ? bsum[tid] : 0;
    int acc = v;
    sh[tid] = acc; __syncthreads();
    for (int off = 1; off < 512; off <<= 1) {
        int add = (tid >= off) ? sh[tid - off] : 0;
        __syncthreads();
        acc += add;
        sh[tid] = acc;
        __syncthreads();
    }
    if (tid < nb) bsum[tid] = acc - v;
}

__global__ void k_scan3(int* __restrict__ rowptr, const int* __restrict__ bsum)
{
    int i = blockIdx.x * 256 + threadIdx.x;
    if (i <= N_NODES) rowptr[i] += bsum[blockIdx.x];
}

__global__ void k_scatter(const int* __restrict__ ei, const int* __restrict__ rowptr,
                          const int* __restrict__ pos, int* __restrict__ srcs)
{
    int e = blockIdx.x * blockDim.x + threadIdx.x;
    if (e >= E_TOT) return;
    int src = (e < N_EDGES) ? ei[e] : (e - N_EDGES);
    int dst = (e < N_EDGES) ? ei[N_EDGES + e] : (e - N_EDGES);
    srcs[rowptr[dst] + pos[e]] = src;
}

// ---------------------------------------------------------------------------
// Layer-1 aggregation in x-space (16 lanes per node, one edge per lane):
//   agg_h[n] = sum_e w_e^h * x[src_e]  (4 dims/head), ws_h[n] = sum_e w_e^h
// Attention logits computed inline from x[s].A1 / x[n].D1 (exact algebra).
// x is 1.6 MB -> L2-resident; per-edge traffic ~20B, all L2 hits.
// ---------------------------------------------------------------------------
__global__ void __launch_bounds__(256) k_gather1x(
    const int* __restrict__ srcs, const int* __restrict__ rowptr, const int* __restrict__ deg,
    const float* __restrict__ x,
    const float* __restrict__ A1c, const float* __restrict__ D1c,
    float4* __restrict__ agg0, float4* __restrict__ agg1, float2* __restrict__ wsA)
{
    const int tid  = threadIdx.x;
    const int n    = blockIdx.x * 16 + (tid >> 4);
    const int lane = tid & 15;
    if (n >= N_NODES) return;

    const float4 A0 = ((const float4*)A1c)[0], A1v = ((const float4*)A1c)[1];
    const float4 D0 = ((const float4*)D1c)[0], D1v = ((const float4*)D1c)[1];
    const float4 xn = ((const float4*)x)[n];
    const float ad0 = xn.x * D0.x + xn.y * D0.y + xn.z * D0.z + xn.w * D0.w;
    const float ad1 = xn.x * D1v.x + xn.y * D1v.y + xn.z * D1v.z + xn.w * D1v.w;

    const int beg = rowptr[n], rend = beg + deg[n];
    float4 acc0 = {0.f, 0.f, 0.f, 0.f}, acc1 = {0.f, 0.f, 0.f, 0.f};
    float ws0 = 0.f, ws1 = 0.f;
    for (int j = beg + lane; j < rend; j += 16) {
        const int s = srcs[j];
        const float4 xs = ((const float4*)x)[s];
        const float as0 = xs.x * A0.x + xs.y * A0.y + xs.z * A0.z + xs.w * A0.w;
        const float as1 = xs.x * A1v.x + xs.y * A1v.y + xs.z * A1v.z + xs.w * A1v.w;
        const float w0 = __expf(lrelu(as0 + ad0));
        const float w1 = __expf(lrelu(as1 + ad1));
        acc0.x = fmaf(w0, xs.x, acc0.x); acc0.y = fmaf(w0, xs.y, acc0.y);
        acc0.z = fmaf(w0, xs.z, acc0.z); acc0.w = fmaf(w0, xs.w, acc0.w);
        acc1.x = fmaf(w1, xs.x, acc1.x); acc1.y = fmaf(w1, xs.y, acc1.y);
        acc1.z = fmaf(w1, xs.z, acc1.z); acc1.w = fmaf(w1, xs.w, acc1.w);
        ws0 += w0; ws1 += w1;
    }
    #pragma unroll
    for (int off = 1; off < 16; off <<= 1) {
        acc0.x += __shfl_xor(acc0.x, off, 64);
        acc0.y += __shfl_xor(acc0.y, off, 64);
        acc0.z += __shfl_xor(acc0.z, off, 64);
        acc0.w += __shfl_xor(acc0.w, off, 64);
        acc1.x += __shfl_xor(acc1.x, off, 64);
        acc1.y += __shfl_xor(acc1.y, off, 64);
        acc1.z += __shfl_xor(acc1.z, off, 64);
        acc1.w += __shfl_xor(acc1.w, off, 64);
        ws0    += __shfl_xor(ws0,    off, 64);
        ws1    += __shfl_xor(ws1,    off, 64);
    }
    if (lane == 0) {
        agg0[n] = acc0;
        agg1[n] = acc1;
        wsA[n]  = make_float2(ws0, ws1);
    }
}

// ---------------------------------------------------------------------------
// k_h2f: fused  out1 = elu(agg.W1/ws + b1)  (built in LDS, never hits HBM)
//        + as2/ad2 = out1-row . B2/E2
//        + h2 = out1 . W2^T  (register-blocked GEMM), stored fp16
// ---------------------------------------------------------------------------
#define H2_NPB 64
#define SROW_LD 132
__global__ void __launch_bounds__(256) k_h2f(
    const float4* __restrict__ agg0, const float4* __restrict__ agg1,
    const float2* __restrict__ wsA,
    const float* __restrict__ w1, const float* __restrict__ b1,
    const float* __restrict__ w2,
    const float* __restrict__ B2, const float* __restrict__ E2,
    __half* __restrict__ h2h, float* __restrict__ as2, float* __restrict__ ad2)
{
    __shared__ __align__(16) float w2t[128 * 64];          // [k][d]  32 KB
    __shared__ __align__(16) float srow[H2_NPB * SROW_LD]; // out1 rows, padded
    __shared__ __align__(16) float4 sw1[128];
    __shared__ float sb1[128], sB2[128], sE2[128];
    __shared__ float4 sa0[H2_NPB], sa1[H2_NPB];
    __shared__ float2 sws[H2_NPB];
    const int tid = threadIdx.x;
    const int blockNode = blockIdx.x * H2_NPB;

    for (int i = tid; i < 128 * 64; i += 256) {
        int k = i >> 6, d = i & 63;
        w2t[i] = w2[d * 128 + k];
    }
    if (tid < 128) {
        sw1[tid] = ((const float4*)w1)[tid];
        sb1[tid] = b1[tid];
        sB2[tid] = B2[tid];
        sE2[tid] = E2[tid];
    }
    if (tid < H2_NPB) {
        int n = blockNode + tid;
        if (n < N_NODES) { sa0[tid] = agg0[n]; sa1[tid] = agg1[n]; sws[tid] = wsA[n]; }
        else { sa0[tid] = make_float4(0,0,0,0); sa1[tid] = make_float4(0,0,0,0); sws[tid] = make_float2(1.f,1.f); }
    }
    __syncthreads();

    // build out1 rows in LDS
    for (int i = tid; i < H2_NPB * 128; i += 256) {
        int r = i >> 7, c = i & 127, head = c >> 6;
        float4 a = head ? sa1[r] : sa0[r];
        float ws = head ? sws[r].y : sws[r].x;
        float4 w = sw1[c];
        float v = (a.x * w.x + a.y * w.y + a.z * w.z + a.w * w.w) / ws + sb1[c];
        srow[r * SROW_LD + c] = elu_f(v);
    }
    __syncthreads();

    // as2/ad2: 4 threads per node
    {
        int r = tid >> 2, q = tid & 3;
        float ps = 0.f, pd = 0.f;
        for (int c = q * 32; c < q * 32 + 32; ++c) {
            float v = srow[r * SROW_LD + c];
            ps = fmaf(v, sB2[c], ps);
            pd = fmaf(v, sE2[c], pd);
        }
        ps += __shfl_xor(ps, 1, 64); ps += __shfl_xor(ps, 2, 64);
        pd += __shfl_xor(pd, 1, 64); pd += __shfl_xor(pd, 2, 64);
        int n = blockNode + r;
        if (q == 0 && n < N_NODES) { as2[n] = ps; ad2[n] = pd; }
    }

    // GEMM: h2[n,d] = out1[n,:].w2t[:,d]
    const int lane = tid & 63;
    const int wv   = tid >> 6;
    const int q    = lane >> 4;
    const int dg   = lane & 15;
    const int d_base    = dg * 4;
    const int node_base = wv * 16 + q * 4;

    float4 acc[4] = {{0,0,0,0},{0,0,0,0},{0,0,0,0},{0,0,0,0}};
    for (int k = 0; k < 128; k += 4) {
        const float4 w0 = *(const float4*)&w2t[(k + 0) * 64 + d_base];
        const float4 w1v = *(const float4*)&w2t[(k + 1) * 64 + d_base];
        const float4 wq = *(const float4*)&w2t[(k + 2) * 64 + d_base];
        const float4 w3 = *(const float4*)&w2t[(k + 3) * 64 + d_base];
        #pragma unroll
        for (int j = 0; j < 4; ++j) {
            const float4 rv = *(const float4*)&srow[(node_base + j) * SROW_LD + k];
            acc[j].x += rv.x * w0.x + rv.y * w1v.x + rv.z * wq.x + rv.w * w3.x;
            acc[j].y += rv.x * w0.y + rv.y * w1v.y + rv.z * wq.y + rv.w * w3.y;
            acc[j].z += rv.x * w0.z + rv.y * w1v.z + rv.z * wq.z + rv.w * w3.z;
            acc[j].w += rv.x * w0.w + rv.y * w1v.w + rv.z * wq.w + rv.w * w3.w;
        }
    }

    #pragma unroll
    for (int j = 0; j < 4; ++j) {
        int n = blockNode + node_base + j;
        if (n < N_NODES) {
            __half2 p0 = __floats2half2_rn(acc[j].x, acc[j].y);
            __half2 p1 = __floats2half2_rn(acc[j].z, acc[j].w);
            ((__half2*)h2h)[(size_t)n * 32 + dg * 2]     = p0;
            ((__half2*)h2h)[(size_t)n * 32 + dg * 2 + 1] = p1;
        }
    }
}

// ---------------------------------------------------------------------------
// Layer-2 edge weights (coalesced CSR writes); zeroes pad srcs/weights.
// ---------------------------------------------------------------------------
__global__ void __launch_bounds__(256) k_weights2(
    const int* __restrict__ rowptr, const int* __restrict__ deg, int* __restrict__ srcs,
    const float* __restrict__ as2, const float* __restrict__ ad2,
    float* __restrict__ w0p)
{
    int n = blockIdx.x * 16 + (threadIdx.x >> 4);
    int lane = threadIdx.x & 15;
    if (n >= N_NODES) return;
    int beg = rowptr[n], pend = rowptr[n + 1], rend = beg + deg[n];
    float adv = ad2[n];
    for (int j = beg + lane; j < pend; j += 16) {
        if (j < rend) {
            w0p[j] = __expf(lrelu(as2[srcs[j]] + adv));
        } else {
            srcs[j] = 0;     // pad: safe row, zero weight
            w0p[j] = 0.f;
        }
    }
}

// ---------------------------------------------------------------------------
// Gather layer 2: wave per node, lane d = dim d (fp16 row), padded CSR
// ---------------------------------------------------------------------------
__global__ void __launch_bounds__(256) k_gather2(
    const int* __restrict__ srcs, const int* __restrict__ rowptr,
    const float* __restrict__ wcsr,
    const __half* __restrict__ h2h, const float* __restrict__ b2,
    float* __restrict__ out2)
{
    const int tid = threadIdx.x;
    const int n   = blockIdx.x * 4 + (tid >> 6);
    const int d   = tid & 63;
    if (n >= N_NODES) return;
    const int beg = rowptr[n], end = rowptr[n + 1];

    float acc = 0.f, wsum = 0.f;
    for (int j = beg; j < end; j += 4) {
        const int4   s4 = *(const int4*)(srcs + j);
        const float4 w4 = *(const float4*)(wcsr + j);
        const __half v0 = h2h[(size_t)s4.x * 64 + d];
        const __half v1 = h2h[(size_t)s4.y * 64 + d];
        const __half v2 = h2h[(size_t)s4.z * 64 + d];
        const __half v3 = h2h[(size_t)s4.w * 64 + d];
        acc = fmaf(w4.x, __half2float(v0), acc);
        acc = fmaf(w4.y, __half2float(v1), acc);
        acc = fmaf(w4.z, __half2float(v2), acc);
        acc = fmaf(w4.w, __half2float(v3), acc);
        wsum += (w4.x + w4.y) + (w4.z + w4.w);
    }
    out2[(size_t)n * 64 + d] = elu_f(acc / wsum + b2[d]);
}

// ---------------------------------------------------------------------------
// Global mean pool: batch sorted -> register runs, flush at boundaries
// ---------------------------------------------------------------------------
__global__ void __launch_bounds__(256) k_pool(
    const float* __restrict__ out2, const int* __restrict__ batch,
    float* __restrict__ pool, float* __restrict__ cnt)
{
    const int wv = threadIdx.x >> 6, d = threadIdx.x & 63;
    const int wid = blockIdx.x * 4 + wv;
    const int per = (N_NODES + 2047) / 2048;
    int n0 = wid * per, n1 = min(n0 + per, N_NODES);
    if (n0 >= n1) return;
    float acc = 0.f; int g = batch[n0]; int run = 0;
    for (int n = n0; n < n1; ++n) {
        int gn = batch[n];
        if (gn != g) {
            atomicAdd(&pool[g * 64 + d], acc);
            if (d == 0) atomicAdd(&cnt[g], (float)run);
            acc = 0.f; run = 0; g = gn;
        }
        acc += out2[(size_t)n * 64 + d];
        ++run;
    }
    atomicAdd(&pool[g * 64 + d], acc);
    if (d == 0) atomicAdd(&cnt[g], (float)run);
}

__global__ void k_head(const float* __restrict__ pool, const float* __restrict__ cnt,
                       const float* __restrict__ wp, const float* __restrict__ bp,
                       float* __restrict__ out)
{
    int t = threadIdx.x;
    int g = t >> 4, s = t & 15;
    float c = cnt[g]; if (c < 1.f) c = 1.f;
    float acc = bp[s];
    for (int d = 0; d < 64; ++d) acc += (pool[g * 64 + d] / c) * wp[s * 64 + d];
    out[g * 16 + s] = acc;
}

extern "C" void kernel_launch(void* const* d_in, const int* in_sizes, int n_in,
                              void* d_out, int out_size, void* d_ws, size_t ws_size,
                              hipStream_t stream)
{
    const float* x     = (const float*)d_in[0];
    const int*   ei    = (const int*)  d_in[1];
    const int*   batch = (const int*)  d_in[2];
    const float* w1    = (const float*)d_in[3];
    const float* asr1  = (const float*)d_in[4];
    const float* adr1  = (const float*)d_in[5];
    const float* b1    = (const float*)d_in[6];
    const float* w2    = (const float*)d_in[7];
    const float* asr2  = (const float*)d_in[8];
    const float* adr2  = (const float*)d_in[9];
    const float* b2    = (const float*)d_in[10];
    const float* wp    = (const float*)d_in[11];
    const float* bp    = (const float*)d_in[12];
    float* out = (float*)d_out;

    // Workspace layout (~60 MB)
    float4* agg0 = (float4*)d_ws;                          // N
    float4* agg1 = agg0 + N_NODES;                         // N
    float2* wsA  = (float2*)(agg1 + N_NODES);              // N
    __half* h2h  = (__half*)(wsA + N_NODES);               // N*64 fp16
    float* out2  = (float*)(h2h + (size_t)N_NODES * 64);   // N*64 f32
    float* as2   = out2 + (size_t)N_NODES * 64;            // N
    float* ad2   = as2 + N_NODES;                          // N
    float* pool  = ad2 + N_NODES;                          // 64*64
    float* cnt   = pool + N_GRAPHS * 64;                   // 64
    int* deg     = (int*)(cnt + N_GRAPHS);                 // N+1
    int* rowptr  = deg + N_NODES + 1;                      // N+1
    int* pos     = rowptr + N_NODES + 1;                   // E_TOT
    int* srcs    = pos + E_TOT;                            // E_CAP
    float* wcsr  = (float*)(srcs + E_CAP);                 // E_CAP (layer-2 weights)
    int* bsum    = (int*)(wcsr + E_CAP);                   // 512 scan scratch
    float* A1    = (float*)(bsum + 512);                   // 8
    float* D1    = A1 + 8;                                 // 8
    float* B2    = D1 + 8;                                 // 128
    float* E2    = B2 + 128;                               // 128

    hipMemsetAsync(deg, 0, (size_t)(N_NODES + 1) * sizeof(int), stream);
    hipMemsetAsync(pool, 0, (size_t)(N_GRAPHS * 64 + N_GRAPHS) * sizeof(float), stream);

    // Folded attention projections
    k_pre<<<1, 256, 0, stream>>>(w1, asr1, adr1, w2, asr2, adr2, A1, D1, B2, E2);

    // Padded CSR by destination
    const int eb  = (E_TOT + 255) / 256;
    const int nb1 = (N_NODES + 1 + 255) / 256;
    k_count<<<eb, 256, 0, stream>>>(ei, deg, pos);
    k_scan1<<<nb1, 256, 0, stream>>>(deg, rowptr, bsum);
    k_scan2<<<1, 512, 0, stream>>>(bsum, nb1);
    k_scan3<<<nb1, 256, 0, stream>>>(rowptr, bsum);
    k_scatter<<<eb, 256, 0, stream>>>(ei, rowptr, pos, srcs);

    // Layer-1 aggregation in x-space (weights inline, edge-parallel)
    const int gb = (N_NODES + 15) / 16;
    k_gather1x<<<gb, 256, 0, stream>>>(srcs, rowptr, deg, x, A1, D1, agg0, agg1, wsA);

    // Fused out1-build + as2/ad2 + layer-2 GEMM
    k_h2f<<<(N_NODES + H2_NPB - 1) / H2_NPB, 256, 0, stream>>>(
        agg0, agg1, wsA, w1, b1, w2, B2, E2, h2h, as2, ad2);

    // Layer-2 weights + aggregate
    k_weights2<<<gb, 256, 0, stream>>>(rowptr, deg, srcs, as2, ad2, wcsr);
    k_gather2<<<(N_NODES + 3) / 4, 256, 0, stream>>>(srcs, rowptr, wcsr, h2h, b2, out2);

    // Mean pool + head
    k_pool<<<512, 256, 0, stream>>>(out2, batch, pool, cnt);
    k_head<<<1, 1024, 0, stream>>>(pool, cnt, wp, bp, out);
}

// Round 7
// 231.522 us; speedup vs baseline: 1.6869x; 1.1216x over previous
//
#include <hip/hip_runtime.h>
#include <hip/hip_fp16.h>

#define N_NODES  100000
#define N_EDGES  1000000
#define E_TOT    1100000   // edges + self-loops
#define E_CAP    1500000   // padded-CSR capacity (deg padded to x4)
#define N_GRAPHS 64

typedef _Float16 half8 __attribute__((ext_vector_type(8)));
typedef float    f32x4 __attribute__((ext_vector_type(4)));

__device__ __forceinline__ float elu_f(float v) {
    return v > 0.f ? v : expm1f(v);
}

__device__ __forceinline__ float lrelu(float v) {
    return v > 0.f ? v : 0.2f * v;
}

// ---------------------------------------------------------------------------
// k_pre: fold attention vectors through weights (exact algebra):
//   A1[h*4+k] = sum_d W1[(h*64+d)*4+k]*a_src1[h*64+d]  -> as1[n,h] = x[n,:].A1[h]
//   D1 likewise (a_dst1);  B2[k] = sum_d W2[d*128+k]*a_src2[d];  E2 likewise
// ---------------------------------------------------------------------------
__global__ void k_pre(const float* __restrict__ w1,
                      const float* __restrict__ as1v, const float* __restrict__ ad1v,
                      const float* __restrict__ w2,
                      const float* __restrict__ as2v, const float* __restrict__ ad2v,
                      float* __restrict__ A1, float* __restrict__ D1,
                      float* __restrict__ B2, float* __restrict__ E2)
{
    int t = threadIdx.x;
    if (t < 128) {
        float acc = 0.f;
        for (int d = 0; d < 64; ++d) acc += w2[d * 128 + t] * as2v[d];
        B2[t] = acc;
    } else {
        int k = t - 128;
        float acc = 0.f;
        for (int d = 0; d < 64; ++d) acc += w2[d * 128 + k] * ad2v[d];
        E2[k] = acc;
    }
    if (t < 8) {
        int h = t >> 2, k = t & 3;
        float acc = 0.f;
        for (int d = 0; d < 64; ++d) acc += w1[(h * 64 + d) * 4 + k] * as1v[h * 64 + d];
        A1[t] = acc;
    } else if (t < 16) {
        int i = t - 8, h = i >> 2, k = i & 3;
        float acc = 0.f;
        for (int d = 0; d < 64; ++d) acc += w1[(h * 64 + d) * 4 + k] * ad1v[h * 64 + d];
        D1[i] = acc;
    }
}

// ---------------------------------------------------------------------------
// k_pre2: fragment-ordered fp16 W2 for MFMA B-operand.
//   B tile (nt,ks): lane l holds B[k][col], col = nt*16+(l&15),
//   k = ks*32 + (l>>4)*8 + j, j=0..7  ->  contiguous 16B per lane.
//   B[k][col] = w2t[k][col] = w2[col*128 + k].
// ---------------------------------------------------------------------------
__global__ void k_pre2(const float* __restrict__ w2, __half* __restrict__ w2frag)
{
    int f = blockIdx.x * 256 + threadIdx.x;        // 8192 total
    int j = f & 7, ln = (f >> 3) & 63, g = f >> 9; // g = nt*4+ks
    int nt = g >> 2, ks = g & 3;
    int col = nt * 16 + (ln & 15);
    int k   = ks * 32 + ((ln >> 4) << 3) + j;
    w2frag[f] = __float2half(w2[col * 128 + k]);
}

// ---------------------------------------------------------------------------
// CSR build (padded): count -> scan(pad4) -> scatter (srcs only)
// ---------------------------------------------------------------------------
__global__ void k_count(const int* __restrict__ ei, int* __restrict__ deg, int* __restrict__ pos)
{
    int e = blockIdx.x * blockDim.x + threadIdx.x;
    if (e >= E_TOT) return;
    int dst = (e < N_EDGES) ? ei[N_EDGES + e] : (e - N_EDGES);
    pos[e] = atomicAdd(&deg[dst], 1);
}

__global__ void k_scan1(const int* __restrict__ deg, int* __restrict__ rowptr, int* __restrict__ bsum)
{
    __shared__ int sh[256];
    int tid = threadIdx.x;
    int i = blockIdx.x * 256 + tid;
    int v = (i <= N_NODES) ? ((deg[i] + 3) & ~3) : 0;
    int acc = v;
    sh[tid] = acc; __syncthreads();
    for (int off = 1; off < 256; off <<= 1) {
        int add = (tid >= off) ? sh[tid - off] : 0;
        __syncthreads();
        acc += add;
        sh[tid] = acc;
        __syncthreads();
    }
    if (i <= N_NODES) rowptr[i] = acc - v;
    if (tid == 255) bsum[blockIdx.x] = acc;
}

__global__ void k_scan2(int* __restrict__ bsum, int nb)
{
    __shared__ int sh[512];
    int tid = threadIdx.x;
    int v = (tid < nb) ? bsum[tid] : 0;
    int acc = v;
    sh[tid] = acc; __syncthreads();
    for (int off = 1; off < 512; off <<= 1) {
        int add = (tid >= off) ? sh[tid - off] : 0;
        __syncthreads();
        acc += add;
        sh[tid] = acc;
        __syncthreads();
    }
    if (tid < nb) bsum[tid] = acc - v;
}

__global__ void k_scan3(int* __restrict__ rowptr, const int* __restrict__ bsum)
{
    int i = blockIdx.x * 256 + threadIdx.x;
    if (i <= N_NODES) rowptr[i] += bsum[blockIdx.x];
}

__global__ void k_scatter(const int* __restrict__ ei, const int* __restrict__ rowptr,
                          const int* __restrict__ pos, int* __restrict__ srcs)
{
    int e = blockIdx.x * blockDim.x + threadIdx.x;
    if (e >= E_TOT) return;
    int src = (e < N_EDGES) ? ei[e] : (e - N_EDGES);
    int dst = (e < N_EDGES) ? ei[N_EDGES + e] : (e - N_EDGES);
    srcs[rowptr[dst] + pos[e]] = src;
}

// ---------------------------------------------------------------------------
// Layer-1 aggregation in x-space (16 lanes per node, one edge per lane):
//   agg_h[n] = sum_e w_e^h * x[src_e]  (4 dims/head), ws_h[n] = sum_e w_e^h
// ---------------------------------------------------------------------------
__global__ void __launch_bounds__(256) k_gather1x(
    const int* __restrict__ srcs, const int* __restrict__ rowptr, const int* __restrict__ deg,
    const float* __restrict__ x,
    const float* __restrict__ A1c, const float* __restrict__ D1c,
    float4* __restrict__ agg0, float4* __restrict__ agg1, float2* __restrict__ wsA)
{
    const int tid  = threadIdx.x;
    const int n    = blockIdx.x * 16 + (tid >> 4);
    const int lane = tid & 15;
    if (n >= N_NODES) return;

    const float4 A0 = ((const float4*)A1c)[0], A1v = ((const float4*)A1c)[1];
    const float4 D0 = ((const float4*)D1c)[0], D1v = ((const float4*)D1c)[1];
    const float4 xn = ((const float4*)x)[n];
    const float ad0 = xn.x * D0.x + xn.y * D0.y + xn.z * D0.z + xn.w * D0.w;
    const float ad1 = xn.x * D1v.x + xn.y * D1v.y + xn.z * D1v.z + xn.w * D1v.w;

    const int beg = rowptr[n], rend = beg + deg[n];
    float4 acc0 = {0.f, 0.f, 0.f, 0.f}, acc1 = {0.f, 0.f, 0.f, 0.f};
    float ws0 = 0.f, ws1 = 0.f;
    for (int j = beg + lane; j < rend; j += 16) {
        const int s = srcs[j];
        const float4 xs = ((const float4*)x)[s];
        const float as0 = xs.x * A0.x + xs.y * A0.y + xs.z * A0.z + xs.w * A0.w;
        const float as1 = xs.x * A1v.x + xs.y * A1v.y + xs.z * A1v.z + xs.w * A1v.w;
        const float w0 = __expf(lrelu(as0 + ad0));
        const float w1 = __expf(lrelu(as1 + ad1));
        acc0.x = fmaf(w0, xs.x, acc0.x); acc0.y = fmaf(w0, xs.y, acc0.y);
        acc0.z = fmaf(w0, xs.z, acc0.z); acc0.w = fmaf(w0, xs.w, acc0.w);
        acc1.x = fmaf(w1, xs.x, acc1.x); acc1.y = fmaf(w1, xs.y, acc1.y);
        acc1.z = fmaf(w1, xs.z, acc1.z); acc1.w = fmaf(w1, xs.w, acc1.w);
        ws0 += w0; ws1 += w1;
    }
    #pragma unroll
    for (int off = 1; off < 16; off <<= 1) {
        acc0.x += __shfl_xor(acc0.x, off, 64);
        acc0.y += __shfl_xor(acc0.y, off, 64);
        acc0.z += __shfl_xor(acc0.z, off, 64);
        acc0.w += __shfl_xor(acc0.w, off, 64);
        acc1.x += __shfl_xor(acc1.x, off, 64);
        acc1.y += __shfl_xor(acc1.y, off, 64);
        acc1.z += __shfl_xor(acc1.z, off, 64);
        acc1.w += __shfl_xor(acc1.w, off, 64);
        ws0    += __shfl_xor(ws0,    off, 64);
        ws1    += __shfl_xor(ws1,    off, 64);
    }
    if (lane == 0) {
        agg0[n] = acc0;
        agg1[n] = acc1;
        wsA[n]  = make_float2(ws0, ws1);
    }
}

// ---------------------------------------------------------------------------
// k_h2f v2: out1 built as fp16 in LDS (conflict-free), as2/ad2 reduction,
// h2 = out1 . W2^T via MFMA 16x16x32_f16 (B from fragment-ordered global).
// LDS = 17.4 KB -> 8 blocks/CU.
// ---------------------------------------------------------------------------
#define H2_NPB 64
#define SROW_H_LD 136   // halves per row: 272B, 16B-aligned, good bank spread
__global__ void __launch_bounds__(256) k_h2f(
    const float4* __restrict__ agg0, const float4* __restrict__ agg1,
    const float2* __restrict__ wsA,
    const float* __restrict__ w1, const float* __restrict__ b1,
    const __half* __restrict__ w2frag,
    const float* __restrict__ B2, const float* __restrict__ E2,
    __half* __restrict__ h2h, float* __restrict__ as2, float* __restrict__ ad2)
{
    __shared__ __align__(16) _Float16 srow[H2_NPB * SROW_H_LD];
    const int tid = threadIdx.x;
    const int bn  = blockIdx.x * H2_NPB;

    // ---- build out1 rows (fp16): 64 rows x 64 half2, conflict-free writes
    #pragma unroll 4
    for (int t = 0; t < 16; ++t) {
        int i = tid + t * 256;               // 0..4095
        int r = i >> 6, c2 = i & 63;
        int n = bn + r;
        int head = c2 >> 5;
        float4 a; float ws;
        if (n < N_NODES) {
            a = head ? agg1[n] : agg0[n];
            float2 w = wsA[n];
            ws = head ? w.y : w.x;
        } else { a = make_float4(0.f, 0.f, 0.f, 0.f); ws = 1.f; }
        const float4 wA = ((const float4*)w1)[2 * c2];
        const float4 wB = ((const float4*)w1)[2 * c2 + 1];
        const float2 bb = ((const float2*)b1)[c2];
        float inv = 1.f / ws;
        float v0 = elu_f((a.x * wA.x + a.y * wA.y + a.z * wA.z + a.w * wA.w) * inv + bb.x);
        float v1 = elu_f((a.x * wB.x + a.y * wB.y + a.z * wB.z + a.w * wB.w) * inv + bb.y);
        *(__half2*)&srow[r * SROW_H_LD + 2 * c2] = __floats2half2_rn(v0, v1);
    }
    __syncthreads();

    // ---- as2/ad2: 4 threads per node, each covers 32 columns
    {
        int r = tid >> 2, q = tid & 3;
        const __half2* row = (const __half2*)&srow[r * SROW_H_LD];
        float ps = 0.f, pd = 0.f;
        #pragma unroll 4
        for (int i = 0; i < 16; ++i) {
            int c2 = q * 16 + i;
            float2 v  = __half22float2(row[c2]);
            float2 Bv = ((const float2*)B2)[c2];
            float2 Ev = ((const float2*)E2)[c2];
            ps += v.x * Bv.x + v.y * Bv.y;
            pd += v.x * Ev.x + v.y * Ev.y;
        }
        ps += __shfl_xor(ps, 1, 64); ps += __shfl_xor(ps, 2, 64);
        pd += __shfl_xor(pd, 1, 64); pd += __shfl_xor(pd, 2, 64);
        int n = bn + r;
        if (q == 0 && n < N_NODES) { as2[n] = ps; ad2[n] = pd; }
    }

    // ---- GEMM via MFMA: wave wv owns nodes wv*16..+15 (M=16), N=64, K=128
    const int lane = tid & 63;
    const int wv   = tid >> 6;
    const int mrow = lane & 15;
    const int kc   = lane >> 4;
    f32x4 acc[4] = {{0.f,0.f,0.f,0.f},{0.f,0.f,0.f,0.f},{0.f,0.f,0.f,0.f},{0.f,0.f,0.f,0.f}};
    const half8* __restrict__ wf = (const half8*)w2frag;
    #pragma unroll
    for (int ks = 0; ks < 4; ++ks) {
        const half8 af = *(const half8*)&srow[(wv * 16 + mrow) * SROW_H_LD + ks * 32 + kc * 8];
        #pragma unroll
        for (int nt = 0; nt < 4; ++nt) {
            const half8 bf = wf[(nt * 4 + ks) * 64 + lane];
            acc[nt] = __builtin_amdgcn_mfma_f32_16x16x32_f16(af, bf, acc[nt], 0, 0, 0);
        }
    }
    // C/D layout: col = lane&15, row = (lane>>4)*4 + reg  [HW-verified mapping]
    #pragma unroll
    for (int nt = 0; nt < 4; ++nt) {
        #pragma unroll
        for (int reg = 0; reg < 4; ++reg) {
            int node = bn + wv * 16 + ((lane >> 4) << 2) + reg;
            int dim  = nt * 16 + (lane & 15);
            if (node < N_NODES) h2h[(size_t)node * 64 + dim] = __float2half(acc[nt][reg]);
        }
    }
}

// ---------------------------------------------------------------------------
// Layer-2 edge weights (coalesced CSR writes); zeroes pad srcs/weights.
// ---------------------------------------------------------------------------
__global__ void __launch_bounds__(256) k_weights2(
    const int* __restrict__ rowptr, const int* __restrict__ deg, int* __restrict__ srcs,
    const float* __restrict__ as2, const float* __restrict__ ad2,
    float* __restrict__ w0p)
{
    int n = blockIdx.x * 16 + (threadIdx.x >> 4);
    int lane = threadIdx.x & 15;
    if (n >= N_NODES) return;
    int beg = rowptr[n], pend = rowptr[n + 1], rend = beg + deg[n];
    float adv = ad2[n];
    for (int j = beg + lane; j < pend; j += 16) {
        if (j < rend) {
            w0p[j] = __expf(lrelu(as2[srcs[j]] + adv));
        } else {
            srcs[j] = 0;     // pad: safe row, zero weight
            w0p[j] = 0.f;
        }
    }
}

// ---------------------------------------------------------------------------
// Gather layer 2: wave per node, lane d = dim d (fp16 row), padded CSR
// ---------------------------------------------------------------------------
__global__ void __launch_bounds__(256) k_gather2(
    const int* __restrict__ srcs, const int* __restrict__ rowptr,
    const float* __restrict__ wcsr,
    const __half* __restrict__ h2h, const float* __restrict__ b2,
    float* __restrict__ out2)
{
    const int tid = threadIdx.x;
    const int n   = blockIdx.x * 4 + (tid >> 6);
    const int d   = tid & 63;
    if (n >= N_NODES) return;
    const int beg = rowptr[n], end = rowptr[n + 1];

    float acc = 0.f, wsum = 0.f;
    for (int j = beg; j < end; j += 4) {
        const int4   s4 = *(const int4*)(srcs + j);
        const float4 w4 = *(const float4*)(wcsr + j);
        const __half v0 = h2h[(size_t)s4.x * 64 + d];
        const __half v1 = h2h[(size_t)s4.y * 64 + d];
        const __half v2 = h2h[(size_t)s4.z * 64 + d];
        const __half v3 = h2h[(size_t)s4.w * 64 + d];
        acc = fmaf(w4.x, __half2float(v0), acc);
        acc = fmaf(w4.y, __half2float(v1), acc);
        acc = fmaf(w4.z, __half2float(v2), acc);
        acc = fmaf(w4.w, __half2float(v3), acc);
        wsum += (w4.x + w4.y) + (w4.z + w4.w);
    }
    out2[(size_t)n * 64 + d] = elu_f(acc / wsum + b2[d]);
}

// ---------------------------------------------------------------------------
// Global mean pool: batch sorted -> register runs, flush at boundaries
// ---------------------------------------------------------------------------
__global__ void __launch_bounds__(256) k_pool(
    const float* __restrict__ out2, const int* __restrict__ batch,
    float* __restrict__ pool, float* __restrict__ cnt)
{
    const int wv = threadIdx.x >> 6, d = threadIdx.x & 63;
    const int wid = blockIdx.x * 4 + wv;
    const int per = (N_NODES + 2047) / 2048;
    int n0 = wid * per, n1 = min(n0 + per, N_NODES);
    if (n0 >= n1) return;
    float acc = 0.f; int g = batch[n0]; int run = 0;
    for (int n = n0; n < n1; ++n) {
        int gn = batch[n];
        if (gn != g) {
            atomicAdd(&pool[g * 64 + d], acc);
            if (d == 0) atomicAdd(&cnt[g], (float)run);
            acc = 0.f; run = 0; g = gn;
        }
        acc += out2[(size_t)n * 64 + d];
        ++run;
    }
    atomicAdd(&pool[g * 64 + d], acc);
    if (d == 0) atomicAdd(&cnt[g], (float)run);
}

__global__ void k_head(const float* __restrict__ pool, const float* __restrict__ cnt,
                       const float* __restrict__ wp, const float* __restrict__ bp,
                       float* __restrict__ out)
{
    int t = threadIdx.x;
    int g = t >> 4, s = t & 15;
    float c = cnt[g]; if (c < 1.f) c = 1.f;
    float acc = bp[s];
    for (int d = 0; d < 64; ++d) acc += (pool[g * 64 + d] / c) * wp[s * 64 + d];
    out[g * 16 + s] = acc;
}

extern "C" void kernel_launch(void* const* d_in, const int* in_sizes, int n_in,
                              void* d_out, int out_size, void* d_ws, size_t ws_size,
                              hipStream_t stream)
{
    const float* x     = (const float*)d_in[0];
    const int*   ei    = (const int*)  d_in[1];
    const int*   batch = (const int*)  d_in[2];
    const float* w1    = (const float*)d_in[3];
    const float* asr1  = (const float*)d_in[4];
    const float* adr1  = (const float*)d_in[5];
    const float* b1    = (const float*)d_in[6];
    const float* w2    = (const float*)d_in[7];
    const float* asr2  = (const float*)d_in[8];
    const float* adr2  = (const float*)d_in[9];
    const float* b2    = (const float*)d_in[10];
    const float* wp    = (const float*)d_in[11];
    const float* bp    = (const float*)d_in[12];
    float* out = (float*)d_out;

    // Workspace layout (~60 MB)
    float4* agg0 = (float4*)d_ws;                          // N
    float4* agg1 = agg0 + N_NODES;                         // N
    float2* wsA  = (float2*)(agg1 + N_NODES);              // N
    __half* h2h  = (__half*)(wsA + N_NODES);               // N*64 fp16
    float* out2  = (float*)(h2h + (size_t)N_NODES * 64);   // N*64 f32
    float* as2   = out2 + (size_t)N_NODES * 64;            // N
    float* ad2   = as2 + N_NODES;                          // N
    float* pool  = ad2 + N_NODES;                          // 64*64
    float* cnt   = pool + N_GRAPHS * 64;                   // 64
    int* deg     = (int*)(cnt + N_GRAPHS);                 // N+1
    int* rowptr  = deg + N_NODES + 1;                      // N+1
    int* pos     = rowptr + N_NODES + 1;                   // E_TOT
    int* srcs    = pos + E_TOT;                            // E_CAP
    float* wcsr  = (float*)(srcs + E_CAP);                 // E_CAP (layer-2 weights)
    int* bsum    = (int*)(wcsr + E_CAP);                   // 512 scan scratch
    float* A1    = (float*)(bsum + 512);                   // 8
    float* D1    = A1 + 8;                                 // 8
    float* B2    = D1 + 8;                                 // 128
    float* E2    = B2 + 128;                               // 128
    __half* w2frag = (__half*)(E2 + 128);                  // 8192 fp16 (16B-aligned)

    hipMemsetAsync(deg, 0, (size_t)(N_NODES + 1) * sizeof(int), stream);
    hipMemsetAsync(pool, 0, (size_t)(N_GRAPHS * 64 + N_GRAPHS) * sizeof(float), stream);

    // Folded attention projections + fragment-ordered W2
    k_pre<<<1, 256, 0, stream>>>(w1, asr1, adr1, w2, asr2, adr2, A1, D1, B2, E2);
    k_pre2<<<32, 256, 0, stream>>>(w2, w2frag);

    // Padded CSR by destination
    const int eb  = (E_TOT + 255) / 256;
    const int nb1 = (N_NODES + 1 + 255) / 256;
    k_count<<<eb, 256, 0, stream>>>(ei, deg, pos);
    k_scan1<<<nb1, 256, 0, stream>>>(deg, rowptr, bsum);
    k_scan2<<<1, 512, 0, stream>>>(bsum, nb1);
    k_scan3<<<nb1, 256, 0, stream>>>(rowptr, bsum);
    k_scatter<<<eb, 256, 0, stream>>>(ei, rowptr, pos, srcs);

    // Layer-1 aggregation in x-space (weights inline, edge-parallel)
    const int gb = (N_NODES + 15) / 16;
    k_gather1x<<<gb, 256, 0, stream>>>(srcs, rowptr, deg, x, A1, D1, agg0, agg1, wsA);

    // Fused out1-build + as2/ad2 + layer-2 GEMM (MFMA)
    k_h2f<<<(N_NODES + H2_NPB - 1) / H2_NPB, 256, 0, stream>>>(
        agg0, agg1, wsA, w1, b1, w2frag, B2, E2, h2h, as2, ad2);

    // Layer-2 weights + aggregate
    k_weights2<<<gb, 256, 0, stream>>>(rowptr, deg, srcs, as2, ad2, wcsr);
    k_gather2<<<(N_NODES + 3) / 4, 256, 0, stream>>>(srcs, rowptr, wcsr, h2h, b2, out2);

    // Mean pool + head
    k_pool<<<512, 256, 0, stream>>>(out2, batch, pool, cnt);
    k_head<<<1, 1024, 0, stream>>>(pool, cnt, wp, bp, out);
}